// Round 2
// baseline (4000.330 us; speedup 1.0000x reference)
//
#include <hip/hip_runtime.h>

typedef unsigned short u16;
typedef unsigned int u32;

#define N_NODES 64000
#define DIM 64
#define NGRAPH 320
#define NPG 200
#define NEDGE 1024000
#define EPG 3200
#define NSTEPS 5
#define NITERS 6

__device__ __forceinline__ float bf2f(u16 u) {
  u32 x = ((u32)u) << 16;
  float f;
  __builtin_memcpy(&f, &x, 4);
  return f;
}
__device__ __forceinline__ u16 f2bf(float f) {
  u32 x;
  __builtin_memcpy(&x, &f, 4);
  x = (x + 0x7FFFu + ((x >> 16) & 1u)) >> 16;
  return (u16)x;
}
__device__ __forceinline__ float sigmf(float x) { return 1.0f / (1.0f + __expf(-x)); }

// ---------------- prep kernels ----------------

__global__ void k_pack(const int* __restrict__ src, const int* __restrict__ dst,
                       const int* __restrict__ ety, u32* __restrict__ packed) {
  int e = blockIdx.x * 256 + threadIdx.x;
  if (e < NEDGE) {
    int g = e / EPG;
    int base = g * NPG;
    packed[e] = (u32)(src[e] - base) | ((u32)(dst[e] - base) << 8) | ((u32)ety[e] << 16);
  }
}

__global__ void k_transpose(const float* __restrict__ src, float* __restrict__ dst, int R, int C) {
  int i = blockIdx.x * 256 + threadIdx.x;
  if (i < R * C) {
    int r = i / C, c = i - r * C;
    dst[c * R + r] = src[i];
  }
}

// ---------------- per-step kernels ----------------

// Wh[t][n][o] = sum_d h[n][d] * W_edge[t][d][o] + b_edge[t][o], stored bf16
// block: 64 nodes x 1 etype; thread (o = tid&63, nodelane = tid>>6); W column in registers
__global__ void __launch_bounds__(256) k_wh(const float* __restrict__ h,
                                            const float* __restrict__ W_edge,
                                            const float* __restrict__ b_edge,
                                            u16* __restrict__ Whb) {
  __shared__ __align__(16) float h_s[64 * 64];
  int tid = threadIdx.x;
  int o = tid & 63, nl = tid >> 6;
  int t = blockIdx.y;
  int n0 = blockIdx.x * 64;
  for (int i = tid; i < 4096; i += 256) h_s[i] = h[(size_t)n0 * 64 + i];
  float wcol[64];
#pragma unroll
  for (int k = 0; k < 64; k++) wcol[k] = W_edge[(t * 64 + k) * 64 + o];
  float bias = b_edge[t * 64 + o];
  __syncthreads();
  for (int ng = 0; ng < 16; ng++) {
    int n = ng * 4 + nl;
    float acc = bias;
#pragma unroll
    for (int k4 = 0; k4 < 16; k4++) {
      float4 hv = *(const float4*)&h_s[n * 64 + k4 * 4];
      acc += hv.x * wcol[k4 * 4] + hv.y * wcol[k4 * 4 + 1] +
             hv.z * wcol[k4 * 4 + 2] + hv.w * wcol[k4 * 4 + 3];
    }
    Whb[((size_t)t * N_NODES + n0 + n) * 64 + o] = f2bf(acc);
  }
}

// one block per graph (512 threads = 8 waves): LDS fp32 accumulator,
// wave-per-edge gather + LDS atomic scatter
__global__ void __launch_bounds__(512) k_scatter(const u16* __restrict__ Whb,
                                                 const u32* __restrict__ packed,
                                                 float* __restrict__ a) {
  __shared__ float acc[NPG * 64];
  int g = blockIdx.x;
  int tid = threadIdx.x;
  int lane = tid & 63, wid = tid >> 6;
  for (int i = tid; i < NPG * 64; i += 512) acc[i] = 0.f;
  __syncthreads();
  const u32* pg = packed + g * EPG;
  size_t nodebase = (size_t)g * NPG;
  for (int i = wid; i < EPG; i += 8) {
    u32 p = pg[i];
    int s = p & 255;
    int dl = (p >> 8) & 255;
    int t = (p >> 16) & 7;
    float v = bf2f(Whb[((size_t)t * N_NODES + nodebase + s) * 64 + lane]);
    atomicAdd(&acc[dl * 64 + lane], v);
  }
  __syncthreads();
  float* ag = a + nodebase * 64;
  for (int i = tid; i < NPG * 64; i += 512) ag[i] = acc[i];
}

// GRU: gi = a@W_ih^T + b_ih; gh = h@W_hh^T + b_hh; gate math; h updated in place.
// wt_gru = [W_ih^T | W_hh^T], each [64][192] fp32 (k-major: wt[k*192+j] = W[j][k]).
// Thread j<192 holds column j of both in regs (coalesced global loads across j).
__global__ void __launch_bounds__(256) k_gru(const float* __restrict__ a,
                                             float* __restrict__ h,
                                             const float* __restrict__ wt_gru,
                                             const float* __restrict__ b_ih,
                                             const float* __restrict__ b_hh) {
  __shared__ __align__(16) float a_s[32 * 64];
  __shared__ __align__(16) float h_s[32 * 64];
  __shared__ float gsum[32 * 192];  // j<128: gi+gh ; j in [128,192): gi (i_n part)
  __shared__ float ghn[32 * 64];    // h_n part
  int tid = threadIdx.x;
  int nb = blockIdx.x * 32;
  for (int i = tid; i < 2048; i += 256) {
    a_s[i] = a[(size_t)nb * 64 + i];
    h_s[i] = h[(size_t)nb * 64 + i];
  }
  float wih[64], whh[64];
  float bi = 0.f, bh = 0.f;
  int j = tid;
  if (j < 192) {
    bi = b_ih[j];
    bh = b_hh[j];
#pragma unroll
    for (int k = 0; k < 64; k++) {
      wih[k] = wt_gru[k * 192 + j];
      whh[k] = wt_gru[12288 + k * 192 + j];
    }
  }
  __syncthreads();
  if (j < 192) {
    for (int n = 0; n < 32; n++) {
      float gi = bi, gh = bh;
#pragma unroll
      for (int k4 = 0; k4 < 16; k4++) {
        float4 av = *(const float4*)&a_s[n * 64 + k4 * 4];
        float4 hv = *(const float4*)&h_s[n * 64 + k4 * 4];
        gi += av.x * wih[k4 * 4] + av.y * wih[k4 * 4 + 1] + av.z * wih[k4 * 4 + 2] + av.w * wih[k4 * 4 + 3];
        gh += hv.x * whh[k4 * 4] + hv.y * whh[k4 * 4 + 1] + hv.z * whh[k4 * 4 + 2] + hv.w * whh[k4 * 4 + 3];
      }
      if (j < 128) {
        gsum[n * 192 + j] = gi + gh;
      } else {
        gsum[n * 192 + j] = gi;
        ghn[n * 64 + (j - 128)] = gh;
      }
    }
  }
  __syncthreads();
  int d = tid & 63, nl = tid >> 6;
  for (int q = 0; q < 8; q++) {
    int n = q * 4 + nl;
    float r = sigmf(gsum[n * 192 + d]);
    float z = sigmf(gsum[n * 192 + 64 + d]);
    float gg = tanhf(gsum[n * 192 + 128 + d] + r * ghn[n * 64 + d]);
    float hv = h_s[n * 64 + d];
    h[(size_t)(nb + n) * 64 + d] = (1.0f - z) * gg + z * hv;
  }
}

// ---------------- Set2Set: one block per graph, all 6 iterations internal ----------------

__global__ void __launch_bounds__(256) k_set2set(
    const float* __restrict__ feat,
    const float* __restrict__ WTih0, const float* __restrict__ WThh0,
    const float* __restrict__ WTih1, const float* __restrict__ WThh1,
    const float* __restrict__ WTih2, const float* __restrict__ WThh2,
    const float* __restrict__ b_ih0, const float* __restrict__ b_hh0,
    const float* __restrict__ b_ih1, const float* __restrict__ b_hh1,
    const float* __restrict__ b_ih2, const float* __restrict__ b_hh2,
    const float* __restrict__ Wp, const float* __restrict__ bp,
    float* __restrict__ out) {
  __shared__ __align__(16) float feat_s[NPG * 64];
  __shared__ float qstar[128];
  __shared__ float xbuf[128];
  __shared__ float hs_s[3][64];
  __shared__ float cs_s[3][64];
  __shared__ float gates[256];
  __shared__ float e_s[NPG];
  __shared__ float red[4][64];
  __shared__ float scal[2];
  int tid = threadIdx.x;
  int g = blockIdx.x;
  int lane = tid & 63, wid = tid >> 6;
  for (int i = tid; i < NPG * 64; i += 256) feat_s[i] = feat[(size_t)g * NPG * 64 + i];
  if (tid < 128) { qstar[tid] = 0.f; xbuf[tid] = 0.f; }
  if (tid < 64) {
    for (int l = 0; l < 3; l++) { hs_s[l][tid] = 0.f; cs_s[l][tid] = 0.f; }
  }
  __syncthreads();
  for (int it = 0; it < NITERS; it++) {
    // LSTM layer 0 (input = q_star, 128-dim)
    {
      float gj = b_ih0[tid] + b_hh0[tid];
      for (int k = 0; k < 128; k++) gj += qstar[k] * WTih0[k * 256 + tid];
      for (int k = 0; k < 64; k++) gj += hs_s[0][k] * WThh0[k * 256 + tid];
      gates[tid] = gj;
    }
    __syncthreads();
    if (tid < 64) {
      float c = sigmf(gates[64 + tid]) * cs_s[0][tid] + sigmf(gates[tid]) * tanhf(gates[128 + tid]);
      float x = sigmf(gates[192 + tid]) * tanhf(c);
      cs_s[0][tid] = c; hs_s[0][tid] = x; xbuf[tid] = x;
    }
    __syncthreads();
    // layers 1, 2 (input = xbuf, 64-dim)
    for (int l = 1; l < 3; l++) {
      const float* Wi = (l == 1) ? WTih1 : WTih2;
      const float* Wh = (l == 1) ? WThh1 : WThh2;
      const float* bi = (l == 1) ? b_ih1 : b_ih2;
      const float* bh = (l == 1) ? b_hh1 : b_hh2;
      float gj = bi[tid] + bh[tid];
      for (int k = 0; k < 64; k++)
        gj += xbuf[k] * Wi[k * 256 + tid] + hs_s[l][k] * Wh[k * 256 + tid];
      gates[tid] = gj;
      __syncthreads();
      if (tid < 64) {
        float c = sigmf(gates[64 + tid]) * cs_s[l][tid] + sigmf(gates[tid]) * tanhf(gates[128 + tid]);
        float x = sigmf(gates[192 + tid]) * tanhf(c);
        cs_s[l][tid] = c; hs_s[l][tid] = x; xbuf[tid] = x;
      }
      __syncthreads();
    }
    // attention: e_n = dot(feat[n], q) with q = xbuf[0:64]
    for (int n = wid; n < NPG; n += 4) {
      float v = feat_s[n * 64 + lane] * xbuf[lane];
      for (int off = 32; off > 0; off >>= 1) v += __shfl_down(v, off);
      if (lane == 0) e_s[n] = v;
    }
    __syncthreads();
    // segment softmax (single wave)
    if (tid < 64) {
      float m = -1e30f;
      for (int n = lane; n < NPG; n += 64) m = fmaxf(m, e_s[n]);
      for (int off = 32; off > 0; off >>= 1) m = fmaxf(m, __shfl_down(m, off));
      m = __shfl(m, 0);
      float ssum = 0.f;
      for (int n = lane; n < NPG; n += 64) {
        float ex = __expf(e_s[n] - m);
        e_s[n] = ex;
        ssum += ex;
      }
      for (int off = 32; off > 0; off >>= 1) ssum += __shfl_down(ssum, off);
      if (lane == 0) scal[0] = ssum;
    }
    __syncthreads();
    float denom = scal[0];
    {
      float r = 0.f;
      for (int n = wid; n < NPG; n += 4) r += feat_s[n * 64 + lane] * e_s[n];
      red[wid][lane] = r;
    }
    __syncthreads();
    if (tid < 64) {
      float ro = (red[0][lane] + red[1][lane] + red[2][lane] + red[3][lane]) / denom;
      qstar[lane] = xbuf[lane];
      qstar[64 + lane] = ro;
    }
    __syncthreads();
  }
  if (tid < 3) {
    float s = bp[tid];
    for (int k = 0; k < 128; k++) s += qstar[k] * Wp[tid * 128 + k];
    out[g * 3 + tid] = s;
  }
}

// ---------------- host ----------------

extern "C" void kernel_launch(void* const* d_in, const int* in_sizes, int n_in,
                              void* d_out, int out_size, void* d_ws, size_t ws_size,
                              hipStream_t stream) {
  const float* feats  = (const float*)d_in[0];
  const float* W_edge = (const float*)d_in[1];
  const float* b_edge = (const float*)d_in[2];
  const float* gWih   = (const float*)d_in[3];
  const float* gWhh   = (const float*)d_in[4];
  const float* gbih   = (const float*)d_in[5];
  const float* gbhh   = (const float*)d_in[6];
  const float* lWi0   = (const float*)d_in[7];
  const float* lWh0   = (const float*)d_in[8];
  const float* lbi0   = (const float*)d_in[9];
  const float* lbh0   = (const float*)d_in[10];
  const float* lWi1   = (const float*)d_in[11];
  const float* lWh1   = (const float*)d_in[12];
  const float* lbi1   = (const float*)d_in[13];
  const float* lbh1   = (const float*)d_in[14];
  const float* lWi2   = (const float*)d_in[15];
  const float* lWh2   = (const float*)d_in[16];
  const float* lbi2   = (const float*)d_in[17];
  const float* lbh2   = (const float*)d_in[18];
  const float* Wp     = (const float*)d_in[19];
  const float* bp     = (const float*)d_in[20];
  const int* src      = (const int*)d_in[21];
  const int* dst      = (const int*)d_in[22];
  const int* ety      = (const int*)d_in[23];
  float* out = (float*)d_out;

  char* ws = (char*)d_ws;
  float* h      = (float*)ws;                    // 16,384,000 B
  float* a      = (float*)(ws + 16384000);       // 16,384,000 B
  u16*   Whb    = (u16*)(ws + 32768000);         // 49,152,000 B
  u32*   packed = (u32*)(ws + 81920000);         //  4,096,000 B
  float* wt_gru = (float*)(ws + 86016000);       //     98,304 B
  float* wtl    = (float*)(ws + 86114304);       //    458,752 B
  float* WTih0 = wtl;
  float* WThh0 = WTih0 + 32768;
  float* WTih1 = WThh0 + 16384;
  float* WThh1 = WTih1 + 16384;
  float* WTih2 = WThh1 + 16384;
  float* WThh2 = WTih2 + 16384;

  k_pack<<<NEDGE / 256, 256, 0, stream>>>(src, dst, ety, packed);
  k_transpose<<<48, 256, 0, stream>>>(gWih, wt_gru, 192, 64);
  k_transpose<<<48, 256, 0, stream>>>(gWhh, wt_gru + 12288, 192, 64);
  k_transpose<<<128, 256, 0, stream>>>(lWi0, WTih0, 256, 128);
  k_transpose<<<64, 256, 0, stream>>>(lWh0, WThh0, 256, 64);
  k_transpose<<<64, 256, 0, stream>>>(lWi1, WTih1, 256, 64);
  k_transpose<<<64, 256, 0, stream>>>(lWh1, WThh1, 256, 64);
  k_transpose<<<64, 256, 0, stream>>>(lWi2, WTih2, 256, 64);
  k_transpose<<<64, 256, 0, stream>>>(lWh2, WThh2, 256, 64);
  hipMemcpyAsync(h, feats, (size_t)N_NODES * DIM * sizeof(float),
                 hipMemcpyDeviceToDevice, stream);

  for (int s = 0; s < NSTEPS; s++) {
    k_wh<<<dim3(N_NODES / 64, 6), 256, 0, stream>>>(h, W_edge, b_edge, Whb);
    k_scatter<<<NGRAPH, 512, 0, stream>>>(Whb, packed, a);
    k_gru<<<N_NODES / 32, 256, 0, stream>>>(a, h, wt_gru, gbih, gbhh);
  }
  k_set2set<<<NGRAPH, 256, 0, stream>>>(h, WTih0, WThh0, WTih1, WThh1, WTih2, WThh2,
                                        lbi0, lbh0, lbi1, lbh1, lbi2, lbh2, Wp, bp, out);
}